// Round 1
// baseline (16617.024 us; speedup 1.0000x reference)
//
#include <hip/hip_runtime.h>
#include <cfloat>
#include <cmath>

#define B_       4
#define T_       512
#define D_       1024
#define H_       8
#define DH_      128
#define DEPTH_   4
#define V_       32000
#define MEMLEN_  512
#define CMEMLEN_ 128
#define KV_      1152   // CMEMLEN_ + MEMLEN_ + T_

static __device__ __forceinline__ float sigmoidf_(float x) { return 1.0f / (1.0f + expf(-x)); }

// ---------------------------------------------------------------------------
// Embedding gather: x[row] = token_emb[tokens[row]]   (row = b*T + t)
// ---------------------------------------------------------------------------
__global__ void embed_kernel(const int* __restrict__ tokens,
                             const float* __restrict__ emb,
                             float* __restrict__ x)
{
    int row = blockIdx.x;
    int tok = tokens[row];
    const float4* src = (const float4*)&emb[(size_t)tok * D_];
    float4* dst = (float4*)&x[(size_t)row * D_];
    dst[threadIdx.x] = src[threadIdx.x];
}

// ---------------------------------------------------------------------------
// LayerNorm over D=1024. One block (256 threads) per row.
// ---------------------------------------------------------------------------
__global__ __launch_bounds__(256)
void ln_kernel(const float* __restrict__ x,
               const float* __restrict__ g,
               const float* __restrict__ b,
               float* __restrict__ y)
{
    __shared__ float red[10];
    int row = blockIdx.x;
    float4 v = ((const float4*)&x[(size_t)row * D_])[threadIdx.x];
    float s  = v.x + v.y + v.z + v.w;
    float ss = v.x*v.x + v.y*v.y + v.z*v.z + v.w*v.w;
    #pragma unroll
    for (int off = 32; off >= 1; off >>= 1) {
        s  += __shfl_down(s,  off, 64);
        ss += __shfl_down(ss, off, 64);
    }
    int lane = threadIdx.x & 63, w = threadIdx.x >> 6;
    if (lane == 0) { red[w] = s; red[4 + w] = ss; }
    __syncthreads();
    if (threadIdx.x == 0) {
        float S  = red[0] + red[1] + red[2] + red[3];
        float SS = red[4] + red[5] + red[6] + red[7];
        float mean = S * (1.0f / (float)D_);
        float var  = SS * (1.0f / (float)D_) - mean * mean;
        red[8] = mean;
        red[9] = rsqrtf(var + 1e-5f);
    }
    __syncthreads();
    float mean = red[8], rstd = red[9];
    int c = threadIdx.x * 4;
    float4 gv = *(const float4*)&g[c];
    float4 bv = *(const float4*)&b[c];
    float4 o;
    o.x = (v.x - mean) * rstd * gv.x + bv.x;
    o.y = (v.y - mean) * rstd * gv.y + bv.y;
    o.z = (v.z - mean) * rstd * gv.z + bv.z;
    o.w = (v.w - mean) * rstd * gv.w + bv.w;
    *(float4*)&y[(size_t)row * D_ + c] = o;
}

// ---------------------------------------------------------------------------
// Gather kv_in rows: [cmem(128) | mem(512) | xn(512)] per batch.
// ---------------------------------------------------------------------------
__global__ void gather_kvin_kernel(const float* __restrict__ cmem_l,
                                   const float* __restrict__ mem_l,
                                   const float* __restrict__ xn,
                                   float* __restrict__ kvin)
{
    int row = blockIdx.x;      // 0..B*KV-1
    int b = row / KV_;
    int j = row % KV_;
    const float* src;
    if (j < CMEMLEN_)                src = cmem_l + ((size_t)b * CMEMLEN_ + j) * D_;
    else if (j < CMEMLEN_ + MEMLEN_) src = mem_l  + ((size_t)b * MEMLEN_ + (j - CMEMLEN_)) * D_;
    else                             src = xn     + ((size_t)b * T_ + (j - CMEMLEN_ - MEMLEN_)) * D_;
    ((float4*)&kvin[(size_t)row * D_])[threadIdx.x] = ((const float4*)src)[threadIdx.x];
}

// ---------------------------------------------------------------------------
// Tiled SGEMM: C(M,N) = A(M,K) @ B(K,N) [+bias] [gelu].
// TRB=1: B is (N,K) row-major, used transposed (nn.Linear style).
// Requires M%128==0, N%128==0, K%8==0 (true for every GEMM here).
// 128x128 block tile, 8x8 microtile, Ktile=8, 256 threads.
// ---------------------------------------------------------------------------
template<int EPI, int TRB>   // EPI: 0 none, 1 gelu(exact)
__global__ __launch_bounds__(256)
void gemm_kernel(const float* __restrict__ A, const float* __restrict__ B,
                 const float* __restrict__ bias, float* __restrict__ C,
                 int M, int N, int K)
{
    __shared__ float As[8][128];
    __shared__ float Bs[8][128];
    const int bm = blockIdx.y * 128;
    const int bn = blockIdx.x * 128;
    const int tid = threadIdx.x;
    const int tx = tid & 15;        // n-dim microtile
    const int ty = tid >> 4;        // m-dim microtile
    const int ar = tid >> 1;        // 0..127
    const int ac = (tid & 1) * 4;   // 0 or 4
    const int br = tid >> 5;        // 0..7
    const int bc = (tid & 31) * 4;  // 0..124

    float acc[8][8];
    #pragma unroll
    for (int i = 0; i < 8; ++i)
        #pragma unroll
        for (int j = 0; j < 8; ++j) acc[i][j] = 0.0f;

    const float* Aptr = A + (size_t)(bm + ar) * K + ac;
    for (int k0 = 0; k0 < K; k0 += 8) {
        float4 av = *(const float4*)(Aptr + k0);
        float4 bv;
        if (TRB) bv = *(const float4*)(B + (size_t)(bn + ar) * K + k0 + ac);
        else     bv = *(const float4*)(B + (size_t)(k0 + br) * N + bn + bc);
        __syncthreads();
        As[ac + 0][ar] = av.x; As[ac + 1][ar] = av.y;
        As[ac + 2][ar] = av.z; As[ac + 3][ar] = av.w;
        if (TRB) {
            Bs[ac + 0][ar] = bv.x; Bs[ac + 1][ar] = bv.y;
            Bs[ac + 2][ar] = bv.z; Bs[ac + 3][ar] = bv.w;
        } else {
            *(float4*)&Bs[br][bc] = bv;
        }
        __syncthreads();
        #pragma unroll
        for (int k = 0; k < 8; ++k) {
            float a[8], bb[8];
            *(float4*)&a[0]  = *(const float4*)&As[k][ty * 8];
            *(float4*)&a[4]  = *(const float4*)&As[k][ty * 8 + 4];
            *(float4*)&bb[0] = *(const float4*)&Bs[k][tx * 8];
            *(float4*)&bb[4] = *(const float4*)&Bs[k][tx * 8 + 4];
            #pragma unroll
            for (int i = 0; i < 8; ++i)
                #pragma unroll
                for (int j = 0; j < 8; ++j)
                    acc[i][j] = fmaf(a[i], bb[j], acc[i][j]);
        }
    }
    #pragma unroll
    for (int i = 0; i < 8; ++i) {
        int m = bm + ty * 8 + i;
        float* crow = C + (size_t)m * N + bn;
        #pragma unroll
        for (int j = 0; j < 8; ++j) {
            float v = acc[i][j];
            if (bias) v += bias[bn + tx * 8 + j];
            if (EPI == 1) v = 0.5f * v * (1.0f + erff(v * 0.70710678118654752f));
            crow[tx * 8 + j] = v;
        }
    }
}

// ---------------------------------------------------------------------------
// QK^T (MODE 0) and shifted positional QP^T scatter-add (MODE 1), one batch.
// Q: (T, D) slice; KVm: (KV, 2048) k|v rows; POS: (H, KV, DH); dots: (H,T,KV).
// 64x64 output tile, full K=128 dot in one LDS stage.
// ---------------------------------------------------------------------------
#define NEG_MASK (-FLT_MAX)
static constexpr float ATTN_SCALE = 0.088388347648318447f;  // 128^-0.5

template<int MODE>
__global__ __launch_bounds__(256)
void qkt_kernel(const float* __restrict__ Q,
                const float* __restrict__ KVm,
                const float* __restrict__ POS,
                float* __restrict__ dots)
{
    const int h  = blockIdx.z;
    const int r0 = blockIdx.y * 64;
    const int j0 = blockIdx.x * 64;
    __shared__ float Qs[128][64];   // [k][r]
    __shared__ float Bs[128][64];   // [k][j]
    const int tid = threadIdx.x;

    #pragma unroll
    for (int rep = 0; rep < 8; ++rep) {
        int fidx = tid + rep * 256;       // 2048 float4s total
        int row = fidx >> 5;              // 0..63
        int c4  = (fidx & 31) * 4;        // 0..124
        float4 v = *(const float4*)&Q[(size_t)(r0 + row) * D_ + h * DH_ + c4];
        Qs[c4 + 0][row] = v.x; Qs[c4 + 1][row] = v.y;
        Qs[c4 + 2][row] = v.z; Qs[c4 + 3][row] = v.w;
        float4 w;
        if constexpr (MODE == 0)
            w = *(const float4*)&KVm[(size_t)(j0 + row) * 2048 + h * DH_ + c4];
        else
            w = *(const float4*)&POS[((size_t)h * KV_ + j0 + row) * DH_ + c4];
        Bs[c4 + 0][row] = w.x; Bs[c4 + 1][row] = w.y;
        Bs[c4 + 2][row] = w.z; Bs[c4 + 3][row] = w.w;
    }
    __syncthreads();

    const int tx = tid & 15;   // j quad
    const int ty = tid >> 4;   // r quad
    float acc[4][4] = {};
    for (int k = 0; k < 128; ++k) {
        float a[4], b[4];
        *(float4*)a = *(const float4*)&Qs[k][ty * 4];
        *(float4*)b = *(const float4*)&Bs[k][tx * 4];
        #pragma unroll
        for (int i = 0; i < 4; ++i)
            #pragma unroll
            for (int j = 0; j < 4; ++j)
                acc[i][j] = fmaf(a[i], b[j], acc[i][j]);
    }

    #pragma unroll
    for (int i = 0; i < 4; ++i) {
        int r = r0 + ty * 4 + i;
        #pragma unroll
        for (int j = 0; j < 4; ++j) {
            if constexpr (MODE == 0) {
                int jj = j0 + tx * 4 + j;
                float val = (jj <= r + 640) ? acc[i][j] * ATTN_SCALE : NEG_MASK;
                dots[((size_t)h * T_ + r) * KV_ + jj] = val;
            } else {
                int jp = j0 + tx * 4 + j;
                int jj = jp - 511 + r;     // shifted column; jj<KV_ always holds
                if (jj >= 0)
                    dots[((size_t)h * T_ + r) * KV_ + jj] += acc[i][j] * ATTN_SCALE;
            }
        }
    }
}

// ---------------------------------------------------------------------------
// Row softmax over KV with causal band (valid j <= r+640); zeros masked tail.
// ---------------------------------------------------------------------------
__global__ __launch_bounds__(256)
void softmax_kernel(float* __restrict__ dots)
{
    __shared__ float red[5];
    const int r = blockIdx.x;
    const int h = blockIdx.y;
    float* row = dots + ((size_t)h * T_ + r) * KV_;
    int L = r + 641; if (L > KV_) L = KV_;
    int tid = threadIdx.x;
    int lane = tid & 63, w = tid >> 6;

    float m = -FLT_MAX;
    for (int j = tid; j < L; j += 256) m = fmaxf(m, row[j]);
    #pragma unroll
    for (int off = 32; off >= 1; off >>= 1) m = fmaxf(m, __shfl_down(m, off, 64));
    if (lane == 0) red[w] = m;
    __syncthreads();
    if (tid == 0) red[4] = fmaxf(fmaxf(red[0], red[1]), fmaxf(red[2], red[3]));
    __syncthreads();
    m = red[4];

    float s = 0.0f;
    for (int j = tid; j < L; j += 256) {
        float e = expf(row[j] - m);
        row[j] = e;
        s += e;
    }
    __syncthreads();
    #pragma unroll
    for (int off = 32; off >= 1; off >>= 1) s += __shfl_down(s, off, 64);
    if (lane == 0) red[w] = s;
    __syncthreads();
    if (tid == 0) red[4] = red[0] + red[1] + red[2] + red[3];
    __syncthreads();
    float inv = 1.0f / red[4];

    for (int j = tid; j < L; j += 256) row[j] *= inv;
    for (int j = L + tid; j < KV_; j += 256) row[j] = 0.0f;
}

// ---------------------------------------------------------------------------
// attn @ V, one batch. out tile: 32 rows x 128 (one head's dh).
// ---------------------------------------------------------------------------
__global__ __launch_bounds__(256)
void attnv_kernel(const float* __restrict__ dots,  // (H,T,KV)
                  const float* __restrict__ KVm,   // (KV, 2048)
                  float* __restrict__ out)         // (T, D)
{
    const int h  = blockIdx.y;
    const int r0 = blockIdx.x * 32;
    __shared__ float As[64][32];    // [k][r]
    __shared__ float Vs[64][128];   // [k][dh]
    const int tid = threadIdx.x;
    const int tx = tid & 31;   // dh quad
    const int ty = tid >> 5;   // r quad
    float acc[4][4] = {};

    for (int k0 = 0; k0 < KV_; k0 += 64) {
        __syncthreads();
        #pragma unroll
        for (int rep = 0; rep < 2; ++rep) {
            int fidx = tid + rep * 256;     // 512 float4s (32x64)
            int row = fidx >> 4;            // 0..31
            int c4  = (fidx & 15) * 4;      // 0..60
            float4 v = *(const float4*)&dots[((size_t)h * T_ + r0 + row) * KV_ + k0 + c4];
            As[c4 + 0][row] = v.x; As[c4 + 1][row] = v.y;
            As[c4 + 2][row] = v.z; As[c4 + 3][row] = v.w;
        }
        #pragma unroll
        for (int rep = 0; rep < 8; ++rep) {
            int fidx = tid + rep * 256;     // 2048 float4s (64x128)
            int row = fidx >> 5;            // 0..63
            int c4  = (fidx & 31) * 4;
            *(float4*)&Vs[row][c4] =
                *(const float4*)&KVm[(size_t)(k0 + row) * 2048 + 1024 + h * DH_ + c4];
        }
        __syncthreads();
        for (int k = 0; k < 64; ++k) {
            float a[4], b[4];
            *(float4*)a = *(const float4*)&As[k][ty * 4];
            *(float4*)b = *(const float4*)&Vs[k][tx * 4];
            #pragma unroll
            for (int i = 0; i < 4; ++i)
                #pragma unroll
                for (int j = 0; j < 4; ++j)
                    acc[i][j] = fmaf(a[i], b[j], acc[i][j]);
        }
    }
    #pragma unroll
    for (int i = 0; i < 4; ++i) {
        float* orow = out + (size_t)(r0 + ty * 4 + i) * D_ + h * DH_;
        #pragma unroll
        for (int j = 0; j < 4; ++j) orow[tx * 4 + j] = acc[i][j];
    }
}

// ---------------------------------------------------------------------------
// GRU elementwise: x = (1-z)*n + z*x  (in-place on x)
// ---------------------------------------------------------------------------
__global__ void gru_kernel(const float* __restrict__ gi,
                           const float* __restrict__ gh,
                           float* __restrict__ x)
{
    size_t idx = (size_t)blockIdx.x * 256 + threadIdx.x;
    int row = (int)(idx >> 10);
    int c = (int)(idx & 1023);
    const float* gir = gi + (size_t)row * 3072;
    const float* ghr = gh + (size_t)row * 3072;
    float rr = sigmoidf_(gir[c] + ghr[c]);
    float z  = sigmoidf_(gir[1024 + c] + ghr[1024 + c]);
    float n  = tanhf(gir[2048 + c] + rr * ghr[2048 + c]);
    float h = x[idx];
    x[idx] = (1.0f - z) * n + z * h;
}

// ---------------------------------------------------------------------------
// Permute conv_w (O, I, R) -> Wr (O, R*1024 + I) so conv becomes GEMM-NT.
// ---------------------------------------------------------------------------
__global__ void convw_permute_kernel(const float* __restrict__ w,
                                     float* __restrict__ wr)
{
    size_t idx = (size_t)blockIdx.x * 256 + threadIdx.x;   // over 1024*4096
    int o = (int)(idx >> 12);
    int rem = (int)(idx & 4095);
    int r = rem >> 10;
    int i = rem & 1023;
    wr[idx] = w[((size_t)o * 1024 + i) * 4 + r];
}

// ---------------------------------------------------------------------------

extern "C" void kernel_launch(void* const* d_in, const int* in_sizes, int n_in,
                              void* d_out, int out_size, void* d_ws, size_t ws_size,
                              hipStream_t stream)
{
    const int*   tokens    = (const int*)  d_in[0];
    const float* mem       = (const float*)d_in[1];
    const float* cmem      = (const float*)d_in[2];
    const float* token_emb = (const float*)d_in[3];
    const float* pos_emb   = (const float*)d_in[4];
    const float* logits_w  = (const float*)d_in[5];
    const float* logits_b  = (const float*)d_in[6];
    const float* attn_ln_g = (const float*)d_in[7];
    const float* attn_ln_b = (const float*)d_in[8];
    const float* wq        = (const float*)d_in[9];
    const float* wkv       = (const float*)d_in[10];
    const float* wout      = (const float*)d_in[11];
    const float* bout      = (const float*)d_in[12];
    const float* conv_w    = (const float*)d_in[13];
    const float* conv_b    = (const float*)d_in[14];
    const float* a_wih     = (const float*)d_in[15];
    const float* a_whh     = (const float*)d_in[16];
    const float* a_bih     = (const float*)d_in[17];
    const float* a_bhh     = (const float*)d_in[18];
    const float* ff_ln_g   = (const float*)d_in[19];
    const float* ff_ln_b   = (const float*)d_in[20];
    const float* w1        = (const float*)d_in[21];
    const float* b1        = (const float*)d_in[22];
    const float* w2        = (const float*)d_in[23];
    const float* b2        = (const float*)d_in[24];
    const float* f_wih     = (const float*)d_in[25];
    const float* f_whh     = (const float*)d_in[26];
    const float* f_bih     = (const float*)d_in[27];
    const float* f_bhh     = (const float*)d_in[28];

    // workspace layout (f32 elements), total 39,845,888 floats = ~159.4 MB
    float* W      = (float*)d_ws;
    float* x      = W;                      // 2,097,152
    float* q      = x + 2097152;            // 2,097,152   (reused as yn)
    float* kvin   = q + 2097152;            // 4,718,592   (reused as Wr: 4,194,304)
    float* kvout  = kvin + 4718592;         // 9,437,184   (reused as h1: 8,388,608)
    float* dots   = kvout + 9437184;        // 4,718,592   (one batch: H*T*KV)
    float* attnout= dots + 4718592;         // 2,097,152
    float* proj   = attnout + 2097152;      // 2,097,152   (reused as h2)
    float* g1     = proj + 2097152;         // 6,291,456
    float* g2     = g1 + 6291456;           // 6,291,456

    float* out_logits = (float*)d_out;                                  // B*T*V
    float* out_mems   = out_logits + (size_t)B_ * T_ * V_;              // DEPTH*B*512*1024
    float* out_cmems  = out_mems + (size_t)DEPTH_ * B_ * MEMLEN_ * D_;  // DEPTH*B*128*1024

    embed_kernel<<<B_ * T_, 256, 0, stream>>>(tokens, token_emb, x);

    for (int l = 0; l < DEPTH_; ++l) {
        const float* mem_l  = mem  + (size_t)l * B_ * MEMLEN_ * D_;
        const float* cmem_l = cmem + (size_t)l * B_ * CMEMLEN_ * D_;
        float* xn = out_mems + (size_t)l * B_ * MEMLEN_ * D_;   // new_mems[l] == xn

        // --- attention ---
        ln_kernel<<<B_ * T_, 256, 0, stream>>>(x, attn_ln_g + l * D_, attn_ln_b + l * D_, xn);
        gemm_kernel<0,0><<<dim3(1024/128, 2048/128), 256, 0, stream>>>(
            xn, wq + (size_t)l * D_ * D_, nullptr, q, 2048, 1024, 1024);
        gather_kvin_kernel<<<B_ * KV_, 256, 0, stream>>>(cmem_l, mem_l, xn, kvin);
        gemm_kernel<0,0><<<dim3(2048/128, 4608/128), 256, 0, stream>>>(
            kvin, wkv + (size_t)l * D_ * 2048, nullptr, kvout, 4608, 2048, 1024);

        for (int b = 0; b < B_; ++b) {
            const float* qb  = q + (size_t)b * T_ * D_;
            const float* kvb = kvout + (size_t)b * KV_ * 2048;
            qkt_kernel<0><<<dim3(KV_/64, T_/64, H_), 256, 0, stream>>>(qb, kvb, nullptr, dots);
            qkt_kernel<1><<<dim3(KV_/64, T_/64, H_), 256, 0, stream>>>(qb, nullptr, pos_emb, dots);
            softmax_kernel<<<dim3(T_, H_), 256, 0, stream>>>(dots);
            attnv_kernel<<<dim3(T_/32, H_), 256, 0, stream>>>(dots, kvb, attnout + (size_t)b * T_ * D_);
        }

        gemm_kernel<0,0><<<dim3(1024/128, 2048/128), 256, 0, stream>>>(
            attnout, wout + (size_t)l * D_ * D_, bout + l * D_, proj, 2048, 1024, 1024);

        // --- GRU (attention) ---
        gemm_kernel<0,1><<<dim3(3072/128, 2048/128), 256, 0, stream>>>(
            proj, a_wih + (size_t)l * 3072 * 1024, a_bih + l * 3072, g1, 2048, 3072, 1024);
        gemm_kernel<0,1><<<dim3(3072/128, 2048/128), 256, 0, stream>>>(
            x, a_whh + (size_t)l * 3072 * 1024, a_bhh + l * 3072, g2, 2048, 3072, 1024);
        gru_kernel<<<(2048 * 1024) / 256, 256, 0, stream>>>(g1, g2, x);

        // --- compressed memory: conv as GEMM-NT over permuted weights ---
        convw_permute_kernel<<<(1024 * 4096) / 256, 256, 0, stream>>>(
            conv_w + (size_t)l * D_ * D_ * 4, kvin /* Wr */);
        gemm_kernel<0,1><<<dim3(1024/128, 512/128), 256, 0, stream>>>(
            mem_l, kvin, conv_b + l * D_,
            out_cmems + (size_t)l * B_ * CMEMLEN_ * D_, 512, 1024, 4096);

        // --- feedforward ---
        ln_kernel<<<B_ * T_, 256, 0, stream>>>(x, ff_ln_g + l * D_, ff_ln_b + l * D_, q /* yn */);
        gemm_kernel<1,0><<<dim3(4096/128, 2048/128), 256, 0, stream>>>(
            q, w1 + (size_t)l * D_ * 4096, b1 + l * 4096, kvout /* h1 */, 2048, 4096, 1024);
        gemm_kernel<0,0><<<dim3(1024/128, 2048/128), 256, 0, stream>>>(
            kvout, w2 + (size_t)l * 4096 * D_, b2 + l * D_, proj /* h2 */, 2048, 1024, 4096);

        // --- GRU (ff) ---
        gemm_kernel<0,1><<<dim3(3072/128, 2048/128), 256, 0, stream>>>(
            proj, f_wih + (size_t)l * 3072 * 1024, f_bih + l * 3072, g1, 2048, 3072, 1024);
        gemm_kernel<0,1><<<dim3(3072/128, 2048/128), 256, 0, stream>>>(
            x, f_whh + (size_t)l * 3072 * 1024, f_bhh + l * 3072, g2, 2048, 3072, 1024);
        gru_kernel<<<(2048 * 1024) / 256, 256, 0, stream>>>(g1, g2, x);
    }

    // --- logits ---
    gemm_kernel<0,0><<<dim3(V_/128, 2048/128), 256, 0, stream>>>(
        x, logits_w, logits_b, out_logits, 2048, V_, 1024);
}